// Round 7
// baseline (304.365 us; speedup 1.0000x reference)
//
#include <hip/hip_runtime.h>
#include <math.h>

#define NPTS 200000
#define KNBR 16
#define CDIM 32
#define TEMP 0.1f
#define WEIGHT 0.1f
#define EPSV 1e-8f

#define NSHARD 8
#define SHARD_ROWS 25000u

#define TBL_OFF 256
#define TBL_BYTES (NPTS * CDIM)            // fp8 table: 6,400,000
#define WS_NEEDED ((size_t)(TBL_OFF + TBL_BYTES))

#define MAIN_BLOCKS (NPTS / 64)            // 3125
#define CONVBLK (NPTS * CDIM / 8 / 256)    // 3125

typedef float v2f __attribute__((ext_vector_type(2)));

// ---------------- pre-pass: f32 features -> packed fp8 e4m3 table ----------
__global__ __launch_bounds__(256) void to_fp8(const float* __restrict__ f,
                                              unsigned* __restrict__ o) {
    const int i = blockIdx.x * 256 + threadIdx.x;
    const float4 a = ((const float4*)f)[2 * i];
    const float4 b = ((const float4*)f)[2 * i + 1];
    int w0 = 0, w1 = 0;
    w0 = __builtin_amdgcn_cvt_pk_fp8_f32(a.x, a.y, w0, false);
    w0 = __builtin_amdgcn_cvt_pk_fp8_f32(a.z, a.w, w0, true);
    w1 = __builtin_amdgcn_cvt_pk_fp8_f32(b.x, b.y, w1, false);
    w1 = __builtin_amdgcn_cvt_pk_fp8_f32(b.z, b.w, w1, true);
    ((uint2*)o)[i] = make_uint2((unsigned)w0, (unsigned)w1);
}

// ---------------- main: R4 layout + temporal shard phasing -----------------
// One wave = 16 points = 256 neighbor rows (32B fp8 rows; 2 lanes x 16B each).
// Gather slot j (0..7) of a lane covers row 32j + (lane>>1), chunk (lane&1).
// Phase loop: in phase ph, only slots whose row index lies in shard ph are
// loaded -> chip-wide only ~1 shard (0.8MB) is being fetched at a time, so
// per-XCD L2 converts the random gather into ~compulsory-only misses.
__global__ __launch_bounds__(256) void contrast_fp8_ph(
    const unsigned char* __restrict__ tbl,
    const int* __restrict__ labels,
    const int* __restrict__ nbr,
    float* __restrict__ ws,          // ws[0]=loss sum, ws[1]=valid count
    int* __restrict__ ctr,           // last-done-block counter
    float* __restrict__ out,
    int nblocks) {
    const int lane = threadIdx.x & 63;
    const int wave = threadIdx.x >> 6;
    const int p0 = blockIdx.x * 64 + wave * 16;
    const int h = lane >> 1;
    const int c = lane & 1;
    const int base = p0 * KNBR;

    int idxq[4], labnq[4];
    #pragma unroll
    for (int t = 0; t < 4; ++t) idxq[t] = nbr[base + t * 64 + lane];
    #pragma unroll
    for (int t = 0; t < 4; ++t) labnq[t] = labels[idxq[t]];   // 800KB, L2-hot
    const int labc_l = labels[p0 + (lane & 15)];

    int ridx[8], shj[8];
    #pragma unroll
    for (int j = 0; j < 8; ++j)
        ridx[j] = __shfl(idxq[j >> 1], 32 * (j & 1) + h);
    #pragma unroll
    for (int j = 0; j < 8; ++j)
        shj[j] = (int)((unsigned)ridx[j] / SHARD_ROWS);

    // center rows: hoisted, read once (coalesced-ish stream)
    uint4 cen[8];
    #pragma unroll
    for (int j = 0; j < 8; ++j)
        cen[j] = *(const uint4*)(tbl + (size_t)(p0 + 2 * j + (h >> 4)) * CDIM + 16 * c);

    float dj[8];
    #pragma unroll
    for (int j = 0; j < 8; ++j) dj[j] = 0.f;

    for (int ph = 0; ph < NSHARD; ++ph) {      // NOT unrolled: ph in sgpr
        #pragma unroll
        for (int j = 0; j < 8; ++j) {
            if (shj[j] == ph) {                // uniform across the lane pair
                const uint4 nv = *(const uint4*)(tbl + (size_t)ridx[j] * CDIM + 16 * c);
                const unsigned* pn = (const unsigned*)&nv;
                const unsigned* pc = (const unsigned*)&cen[j];
                float d2 = 0.f;
                #pragma unroll
                for (int q = 0; q < 4; ++q) {
                    v2f nl = __builtin_amdgcn_cvt_pk_f32_fp8((int)pn[q], false);
                    v2f nh = __builtin_amdgcn_cvt_pk_f32_fp8((int)pn[q], true);
                    v2f cl = __builtin_amdgcn_cvt_pk_f32_fp8((int)pc[q], false);
                    v2f ch = __builtin_amdgcn_cvt_pk_f32_fp8((int)pc[q], true);
                    float a0 = cl.x - nl.x, a1 = cl.y - nl.y;
                    float a2 = ch.x - nh.x, a3 = ch.y - nh.y;
                    d2 += a0 * a0 + a1 * a1 + a2 * a2 + a3 * a3;
                }
                d2 += __shfl_xor(d2, 1);       // combine the two 16B halves
                dj[j] = sqrtf(d2 + EPSV);
            }
        }
    }

    // ---- identical R4 softmax/mask/reduction tail ----
    float loss_acc = 0.f, valid_acc = 0.f;
    #pragma unroll
    for (int j = 0; j < 8; ++j) {
        const float d = dj[j];
        float mn = d;
        mn = fminf(mn, __shfl_xor(mn, 2));
        mn = fminf(mn, __shfl_xor(mn, 4));
        mn = fminf(mn, __shfl_xor(mn, 8));
        mn = fminf(mn, __shfl_xor(mn, 16));
        const float e = expf((mn - d) * (1.0f / TEMP));
        const int ln = __shfl(labnq[j >> 1], 32 * (j & 1) + h);
        const int lc = __shfl(labc_l, 2 * j + (h >> 4));
        const bool pos = (ln == lc);
        float pos_s = pos ? e : 0.f;
        float neg_s = e;
        float cnt_s = pos ? 1.f : 0.f;
        #pragma unroll
        for (int off = 2; off <= 16; off <<= 1) {
            pos_s += __shfl_xor(pos_s, off);
            neg_s += __shfl_xor(neg_s, off);
            cnt_s += __shfl_xor(cnt_s, off);
        }
        if (lane == 2 * j || lane == 33 + 2 * j) {
            const int icnt = (int)(cnt_s + 0.5f);
            if (icnt > 0 && icnt < KNBR) {
                loss_acc += -logf(pos_s / neg_s + EPSV);
                valid_acc += 1.f;
            }
        }
    }
    #pragma unroll
    for (int off = 1; off <= 32; off <<= 1) {
        loss_acc += __shfl_xor(loss_acc, off);
        valid_acc += __shfl_xor(valid_acc, off);
    }

    __shared__ float s_loss, s_cnt;
    __shared__ int isLast;
    if (threadIdx.x == 0) { s_loss = 0.f; s_cnt = 0.f; }
    __syncthreads();
    if (lane == 0) { atomicAdd(&s_loss, loss_acc); atomicAdd(&s_cnt, valid_acc); }
    __syncthreads();
    if (threadIdx.x == 0) {
        atomicAdd(&ws[0], s_loss);
        atomicAdd(&ws[1], s_cnt);
        __threadfence();
        isLast = (atomicAdd(ctr, 1) == nblocks - 1);
    }
    __syncthreads();
    if (isLast && threadIdx.x == 0) {
        const float S = atomicAdd(&ws[0], 0.f);   // coherent cross-XCD reads
        const float C = atomicAdd(&ws[1], 0.f);
        out[0] = S / fmaxf(C, 1.f) * WEIGHT;
    }
}

// ---------------- fp32 direct fallback (tiny ws) ---------------------------
__global__ __launch_bounds__(256) void contrast_fp32(
    const float* __restrict__ features,
    const int* __restrict__ labels,
    const int* __restrict__ nbr,
    float* __restrict__ ws) {
    const int lane = threadIdx.x & 63;
    const int wave = threadIdx.x >> 6;
    const int p0 = blockIdx.x * 16 + wave * 4;
    const int m = lane >> 3;
    const int c = lane & 7;
    const int idx_l = nbr[p0 * KNBR + lane];
    const int labn_l = labels[idx_l];
    const int labc_l = labels[p0 + (lane >> 4)];
    float4 cen[4];
    #pragma unroll
    for (int pt = 0; pt < 4; ++pt)
        cen[pt] = *(const float4*)(features + (size_t)(p0 + pt) * CDIM + c * 4);
    int ridx[8];
    #pragma unroll
    for (int j = 0; j < 8; ++j) ridx[j] = __shfl(idx_l, 8 * j + m);
    float4 v[8];
    #pragma unroll
    for (int j = 0; j < 8; ++j)
        v[j] = *(const float4*)(features + (size_t)ridx[j] * CDIM + c * 4);
    float dj[8];
    #pragma unroll
    for (int j = 0; j < 8; ++j) {
        float4 ce = cen[j >> 1];
        float dx = ce.x - v[j].x, dy = ce.y - v[j].y;
        float dz = ce.z - v[j].z, dw = ce.w - v[j].w;
        float d2 = dx * dx + dy * dy + dz * dz + dw * dw;
        d2 += __shfl_xor(d2, 1);
        d2 += __shfl_xor(d2, 2);
        d2 += __shfl_xor(d2, 4);
        dj[j] = sqrtf(d2 + EPSV);
    }
    float loss_acc = 0.f, valid_acc = 0.f;
    #pragma unroll
    for (int pt = 0; pt < 4; ++pt) {
        float a = dj[2 * pt], b = dj[2 * pt + 1];
        float mn = fminf(a, b);
        mn = fminf(mn, __shfl_xor(mn, 8));
        mn = fminf(mn, __shfl_xor(mn, 16));
        mn = fminf(mn, __shfl_xor(mn, 32));
        const float ea = expf((mn - a) / TEMP);
        const float eb = expf((mn - b) / TEMP);
        const int la = __shfl(labn_l, 16 * pt + m);
        const int lb = __shfl(labn_l, 16 * pt + 8 + m);
        const int lc = __shfl(labc_l, 16 * pt);
        float pos_s = (la == lc ? ea : 0.f) + (lb == lc ? eb : 0.f);
        float neg_s = ea + eb;
        float cnt_s = (la == lc ? 1.f : 0.f) + (lb == lc ? 1.f : 0.f);
        #pragma unroll
        for (int off = 8; off <= 32; off <<= 1) {
            pos_s += __shfl_xor(pos_s, off);
            neg_s += __shfl_xor(neg_s, off);
            cnt_s += __shfl_xor(cnt_s, off);
        }
        if (lane == pt) {
            const int icnt = (int)(cnt_s + 0.5f);
            if (icnt > 0 && icnt < KNBR) {
                loss_acc += -logf(pos_s / neg_s + EPSV);
                valid_acc += 1.f;
            }
        }
    }
    __shared__ float s_loss, s_cnt;
    if (threadIdx.x == 0) { s_loss = 0.f; s_cnt = 0.f; }
    __syncthreads();
    if (lane < 4) { atomicAdd(&s_loss, loss_acc); atomicAdd(&s_cnt, valid_acc); }
    __syncthreads();
    if (threadIdx.x == 0) { atomicAdd(&ws[0], s_loss); atomicAdd(&ws[1], s_cnt); }
}

__global__ void contrast_finalize(const float* __restrict__ ws,
                                  float* __restrict__ out) {
    out[0] = ws[0] / fmaxf(ws[1], 1.f) * WEIGHT;
}

extern "C" void kernel_launch(void* const* d_in, const int* in_sizes, int n_in,
                              void* d_out, int out_size, void* d_ws, size_t ws_size,
                              hipStream_t stream) {
    const float* features = (const float*)d_in[0];
    const int* labels     = (const int*)d_in[1];
    const int* nbr        = (const int*)d_in[2];
    float* out = (float*)d_out;
    float* ws  = (float*)d_ws;

    hipMemsetAsync(ws, 0, 16, stream);   // ws[0],ws[1] scalars + ctr + pad

    if (ws_size >= WS_NEEDED) {
        unsigned char* tbl = (unsigned char*)d_ws + TBL_OFF;
        int* ctr = (int*)d_ws + 2;
        to_fp8<<<CONVBLK, 256, 0, stream>>>(features, (unsigned*)tbl);
        contrast_fp8_ph<<<MAIN_BLOCKS, 256, 0, stream>>>(tbl, labels, nbr, ws,
                                                         ctr, out, MAIN_BLOCKS);
    } else {
        contrast_fp32<<<NPTS / 16, 256, 0, stream>>>(features, labels, nbr, ws);
        contrast_finalize<<<1, 1, 0, stream>>>(ws, out);
    }
}